// Round 7
// baseline (76595.667 us; speedup 1.0000x reference)
//
#include <hip/hip_runtime.h>

#define T_ 64
#define B_ 64
#define S_ 128
#define E_ 512
#define H_ 1024

typedef __attribute__((ext_vector_type(4))) float f32x4;

static __device__ __forceinline__ float sigm(float x) {
  return 1.f / (1.f + expf(-x));
}
static __device__ __forceinline__ float dot4(f32x4 a, f32x4 b) {
  return a[0] * b[0] + a[1] * b[1] + a[2] * b[2] + a[3] * b[3];
}

// ---------------------------------------------------------------------------
// Init recurrent state (all f32).  grid = B*H/256 = 256 blocks.
__global__ __launch_bounds__(256) void k_init(const float* __restrict__ h0in,
                                              const float* __restrict__ c0in,
                                              float* __restrict__ h0s,
                                              float* __restrict__ h1s,
                                              float* __restrict__ c0,
                                              float* __restrict__ c1,
                                              float* __restrict__ feed) {
  int i = blockIdx.x * 256 + threadIdx.x;
  h0s[i] = h0in[i];
  h1s[i] = h0in[B_ * H_ + i];
  c0[i] = c0in[i];
  c1[i] = c0in[B_ * H_ + i];
  feed[i] = 0.f;
}

// ---------------------------------------------------------------------------
// Layer-0 LSTM, VALU f32.  grid = dim3(H/256, B); thread = one hidden col j
// of batch b, all 4 gates.  OUTPUTS (hF/cF) are now FLOAT32.
__global__ __launch_bounds__(256) void k_lstm0(
    const float* __restrict__ inp, const float* __restrict__ Wih0,
    const float* __restrict__ bih0, const float* __restrict__ Whh0,
    const float* __restrict__ bhh0, const float* __restrict__ feed,
    const float* __restrict__ h0prev, float* __restrict__ c0,
    float* __restrict__ h0new, float* __restrict__ outhF,
    float* __restrict__ outcF, int t) {
  __shared__ float xs[E_ + 2 * H_];
  const int b = blockIdx.y;
  const int j = blockIdx.x * 256 + threadIdx.x;
  const float* er = inp + ((size_t)t * B_ + b) * E_;
  for (int i = threadIdx.x; i < E_; i += 256) xs[i] = er[i];
  for (int i = threadIdx.x; i < H_; i += 256) xs[E_ + i] = feed[b * H_ + i];
  for (int i = threadIdx.x; i < H_; i += 256) xs[E_ + H_ + i] = h0prev[b * H_ + i];
  __syncthreads();

  float acc[4];
  const float* wih[4];
  const float* whh[4];
#pragma unroll
  for (int q = 0; q < 4; ++q) {
    int n = q * H_ + j;
    acc[q] = bih0[n] + bhh0[n];
    wih[q] = Wih0 + (size_t)n * (E_ + H_);
    whh[q] = Whh0 + (size_t)n * H_;
  }
  for (int k = 0; k < E_ + H_; k += 4) {
    f32x4 xv = *(const f32x4*)(xs + k);
#pragma unroll
    for (int q = 0; q < 4; ++q)
      acc[q] += dot4(xv, *(const f32x4*)(wih[q] + k));
  }
  for (int k = 0; k < H_; k += 4) {
    f32x4 xv = *(const f32x4*)(xs + E_ + H_ + k);
#pragma unroll
    for (int q = 0; q < 4; ++q)
      acc[q] += dot4(xv, *(const f32x4*)(whh[q] + k));
  }
  const int idx = b * H_ + j;
  float cn = sigm(acc[1]) * c0[idx] + sigm(acc[0]) * tanhf(acc[2]);
  float hn = sigm(acc[3]) * tanhf(cn);
  c0[idx] = cn;
  h0new[idx] = hn;
  outhF[idx] = hn;
  outcF[idx] = cn;
}

// ---------------------------------------------------------------------------
// Layer-1 LSTM, VALU f32.  x = [h0new | h1prev].
__global__ __launch_bounds__(256) void k_lstm1(
    const float* __restrict__ h0n, const float* __restrict__ h1prev,
    const float* __restrict__ Wih1, const float* __restrict__ bih1,
    const float* __restrict__ Whh1, const float* __restrict__ bhh1,
    float* __restrict__ c1, float* __restrict__ h1new,
    float* __restrict__ outhF, float* __restrict__ outcF) {
  __shared__ float xs[2 * H_];
  const int b = blockIdx.y;
  const int j = blockIdx.x * 256 + threadIdx.x;
  for (int i = threadIdx.x; i < H_; i += 256) xs[i] = h0n[b * H_ + i];
  for (int i = threadIdx.x; i < H_; i += 256) xs[H_ + i] = h1prev[b * H_ + i];
  __syncthreads();

  float acc[4];
  const float* wih[4];
  const float* whh[4];
#pragma unroll
  for (int q = 0; q < 4; ++q) {
    int n = q * H_ + j;
    acc[q] = bih1[n] + bhh1[n];
    wih[q] = Wih1 + (size_t)n * H_;
    whh[q] = Whh1 + (size_t)n * H_;
  }
  for (int k = 0; k < H_; k += 4) {
    f32x4 xv = *(const f32x4*)(xs + k);
#pragma unroll
    for (int q = 0; q < 4; ++q)
      acc[q] += dot4(xv, *(const f32x4*)(wih[q] + k));
  }
  for (int k = 0; k < H_; k += 4) {
    f32x4 xv = *(const f32x4*)(xs + H_ + k);
#pragma unroll
    for (int q = 0; q < 4; ++q)
      acc[q] += dot4(xv, *(const f32x4*)(whh[q] + k));
  }
  const int idx = b * H_ + j;
  float cn = sigm(acc[1]) * c1[idx] + sigm(acc[0]) * tanhf(acc[2]);
  float hn = sigm(acc[3]) * tanhf(cn);
  c1[idx] = cn;
  h1new[idx] = hn;
  outhF[idx] = hn;
  outcF[idx] = cn;
}

// ---------------------------------------------------------------------------
// q[b,n] = sum_d Wa[n,d] * h1[b,d]   (score identity: score = ctx . q)
__global__ __launch_bounds__(256) void k_q(
    const float* __restrict__ h1, const float* __restrict__ Wa,
    float* __restrict__ q) {
  __shared__ float xs[H_];
  const int b = blockIdx.y;
  const int j = blockIdx.x * 256 + threadIdx.x;
  for (int i = threadIdx.x; i < H_; i += 256) xs[i] = h1[b * H_ + i];
  __syncthreads();
  const float* wr = Wa + (size_t)j * H_;
  float acc = 0.f;
  for (int k = 0; k < H_; k += 4)
    acc += dot4(*(const f32x4*)(xs + k), *(const f32x4*)(wr + k));
  q[b * H_ + j] = acc;
}

// ---------------------------------------------------------------------------
// Attention: scores = ctx . q -> softmax -> cvec.  attns output is FLOAT32.
__global__ __launch_bounds__(256) void k_attn(
    const float* __restrict__ ctx, const float* __restrict__ q,
    float* __restrict__ cvec, float* __restrict__ attns, int t) {
  __shared__ float qs[H_];
  __shared__ float sc[S_];
  const int b = blockIdx.x;
  const int tid = threadIdx.x;
  const int wave = tid >> 6, lane = tid & 63;
  for (int d = tid; d < H_; d += 256) qs[d] = q[b * H_ + d];
  __syncthreads();
  for (int s = wave; s < S_; s += 4) {
    const float* row = ctx + ((size_t)s * B_ + b) * H_;
    float p = 0.f;
#pragma unroll
    for (int c = 0; c < H_; c += 256) {
      int d = c + lane * 4;
      p += dot4(*(const f32x4*)(row + d), *(const f32x4*)(qs + d));
    }
#pragma unroll
    for (int off = 32; off; off >>= 1) p += __shfl_down(p, off);
    if (lane == 0) sc[s] = p;
  }
  __syncthreads();
  if (wave == 0) {
    float m = fmaxf(sc[lane], sc[lane + 64]);
#pragma unroll
    for (int off = 32; off; off >>= 1) m = fmaxf(m, __shfl_down(m, off));
    m = __shfl(m, 0);
    float e0 = expf(sc[lane] - m), e1 = expf(sc[lane + 64] - m);
    float s2 = e0 + e1;
#pragma unroll
    for (int off = 32; off; off >>= 1) s2 += __shfl_down(s2, off);
    s2 = __shfl(s2, 0);
    float inv = 1.f / s2;
    sc[lane] = e0 * inv;
    sc[lane + 64] = e1 * inv;
  }
  __syncthreads();
  float* ao = attns + ((size_t)t * B_ + b) * S_;
  if (tid < S_) ao[tid] = sc[tid];
  float a0 = 0, a1 = 0, a2 = 0, a3 = 0;
  const float* cb = ctx + (size_t)b * H_;
  for (int s = 0; s < S_; ++s) {
    float al = sc[s];
    const float* r = cb + (size_t)s * B_ * H_;
    a0 += al * r[tid];
    a1 += al * r[tid + 256];
    a2 += al * r[tid + 512];
    a3 += al * r[tid + 768];
  }
  cvec[b * H_ + tid] = a0;
  cvec[b * H_ + tid + 256] = a1;
  cvec[b * H_ + tid + 512] = a2;
  cvec[b * H_ + tid + 768] = a3;
}

// ---------------------------------------------------------------------------
// attn_h = tanh([cvec|h1] @ Wout^T); outs is FLOAT32; feed f32.
__global__ __launch_bounds__(256) void k_outproj(
    const float* __restrict__ cvec, const float* __restrict__ h1,
    const float* __restrict__ Wout, float* __restrict__ outs,
    float* __restrict__ feed, int t) {
  __shared__ float xs[2 * H_];
  const int b = blockIdx.y;
  const int j = blockIdx.x * 256 + threadIdx.x;
  for (int i = threadIdx.x; i < H_; i += 256) xs[i] = cvec[b * H_ + i];
  for (int i = threadIdx.x; i < H_; i += 256) xs[H_ + i] = h1[b * H_ + i];
  __syncthreads();
  const float* wr = Wout + (size_t)j * (2 * H_);
  float acc = 0.f;
  for (int k = 0; k < 2 * H_; k += 4)
    acc += dot4(*(const f32x4*)(xs + k), *(const f32x4*)(wr + k));
  float v = tanhf(acc);
  outs[(size_t)t * B_ * H_ + b * H_ + j] = v;
  feed[b * H_ + j] = v;
}

// ---------------------------------------------------------------------------
extern "C" void kernel_launch(void* const* d_in, const int* in_sizes, int n_in,
                              void* d_out, int out_size, void* d_ws, size_t ws_size,
                              hipStream_t stream) {
  const float* inp  = (const float*)d_in[0];
  const float* ctx  = (const float*)d_in[1];
  const float* h0in = (const float*)d_in[2];
  const float* c0in = (const float*)d_in[3];
  const float* Wih0 = (const float*)d_in[4];
  const float* bih0 = (const float*)d_in[5];
  const float* Whh0 = (const float*)d_in[6];
  const float* bhh0 = (const float*)d_in[7];
  const float* Wih1 = (const float*)d_in[8];
  const float* bih1 = (const float*)d_in[9];
  const float* Whh1 = (const float*)d_in[10];
  const float* bhh1 = (const float*)d_in[11];
  const float* Wa   = (const float*)d_in[12];
  const float* Wout = (const float*)d_in[13];

  // d_out is FLOAT32 (reference output dtype is f32; "bf16" in the test label
  // is a hardcoded string).  Outputs concatenated in return order.
  float* out = (float*)d_out;
  float* outs  = out;                              // (T,B,H)
  float* hF    = out + (size_t)T_ * B_ * H_;       // (2,B,H)
  float* cF    = hF + 2 * B_ * H_;                 // (2,B,H)
  float* attns = cF + 2 * B_ * H_;                 // (T,B,S)

  // f32 state workspace, ~2.25 MB
  char* p = (char*)d_ws;
  float* h0s[2];
  float* h1s[2];
  h0s[0] = (float*)p; p += B_ * H_ * 4;
  h0s[1] = (float*)p; p += B_ * H_ * 4;
  h1s[0] = (float*)p; p += B_ * H_ * 4;
  h1s[1] = (float*)p; p += B_ * H_ * 4;
  float* c0   = (float*)p; p += B_ * H_ * 4;
  float* c1   = (float*)p; p += B_ * H_ * 4;
  float* qbuf = (float*)p; p += B_ * H_ * 4;
  float* feed = (float*)p; p += B_ * H_ * 4;
  float* cvec = (float*)p; p += B_ * H_ * 4;

  k_init<<<(B_ * H_) / 256, 256, 0, stream>>>(h0in, c0in, h0s[0], h1s[0],
                                              c0, c1, feed);

  for (int t = 0; t < T_; ++t) {
    int cur = t & 1;
    k_lstm0<<<dim3(H_ / 256, B_), 256, 0, stream>>>(
        inp, Wih0, bih0, Whh0, bhh0, feed, h0s[cur], c0, h0s[cur ^ 1],
        hF, cF, t);
    k_lstm1<<<dim3(H_ / 256, B_), 256, 0, stream>>>(
        h0s[cur ^ 1], h1s[cur], Wih1, bih1, Whh1, bhh1, c1, h1s[cur ^ 1],
        hF + B_ * H_, cF + B_ * H_);
    k_q<<<dim3(H_ / 256, B_), 256, 0, stream>>>(h1s[cur ^ 1], Wa, qbuf);
    k_attn<<<B_, 256, 0, stream>>>(ctx, qbuf, cvec, attns, t);
    k_outproj<<<dim3(H_ / 256, B_), 256, 0, stream>>>(
        cvec, h1s[cur ^ 1], Wout, outs, feed, t);
  }
}

// Round 8
// 9615.234 us; speedup vs baseline: 7.9661x; 7.9661x over previous
//
#include <hip/hip_runtime.h>

#define T_ 64
#define B_ 64
#define S_ 128
#define E_ 512
#define H_ 1024

typedef __attribute__((ext_vector_type(8))) short short8;
typedef __attribute__((ext_vector_type(4))) short short4v;
typedef __attribute__((ext_vector_type(4))) float f32x4;

static __device__ __forceinline__ float bf2f(ushort u) {
  union { float f; unsigned u; } x; x.u = ((unsigned)u) << 16; return x.f;
}
static __device__ __forceinline__ ushort f2bf(float f) {
  union { float f; unsigned u; } x; x.f = f;
  unsigned r = 0x7FFFu + ((x.u >> 16) & 1u);
  return (ushort)((x.u + r) >> 16);
}
static __device__ __forceinline__ float sigm(float x) {
  return 1.f / (1.f + expf(-x));
}

// ---------------------------------------------------------------------------
// f32 -> bf16 conversion, 4 elems/thread.
__global__ __launch_bounds__(256) void k_cvt(const float* __restrict__ src,
                                             ushort* __restrict__ dst, int n4) {
  int i = blockIdx.x * 256 + threadIdx.x;
  if (i >= n4) return;
  f32x4 v = ((const f32x4*)src)[i];
  short4v o;
  o[0] = (short)f2bf(v[0]); o[1] = (short)f2bf(v[1]);
  o[2] = (short)f2bf(v[2]); o[3] = (short)f2bf(v[3]);
  ((short4v*)dst)[i] = o;
}

// ---------------------------------------------------------------------------
// Init recurrent state: h bf16, c f32, feed bf16 zero.
__global__ __launch_bounds__(256) void k_init(const float* __restrict__ h0in,
                                              const float* __restrict__ c0in,
                                              ushort* __restrict__ h0bf,
                                              ushort* __restrict__ h1bf,
                                              float* __restrict__ c0s,
                                              float* __restrict__ c1s,
                                              ushort* __restrict__ feed) {
  int i = blockIdx.x * 256 + threadIdx.x;
  h0bf[i] = f2bf(h0in[i]);
  h1bf[i] = f2bf(h0in[B_ * H_ + i]);
  c0s[i] = c0in[i];
  c1s[i] = c0in[B_ * H_ + i];
  feed[i] = 0;
}

// ---------------------------------------------------------------------------
// Layer-0 LSTM (MFMA bf16): gates = [emb|feed]@Wih0^T + h0prev@Whh0^T + b.
// grid = H/16 = 64 blocks; block owns j-cols [j0,j0+16) for ALL 4 gates;
// 4 waves = 4 batch strips of 16.  Weights read once per dispatch.
__global__ __launch_bounds__(256) void k_lstm0(
    const ushort* __restrict__ inp, const ushort* __restrict__ Wih0,
    const float* __restrict__ bih0, const ushort* __restrict__ Whh0,
    const float* __restrict__ bhh0, const ushort* __restrict__ feed,
    const ushort* __restrict__ h0prev, float* __restrict__ c0s,
    ushort* __restrict__ h0new, float* __restrict__ outhF,
    float* __restrict__ outcF, int t) {
  const int tid = threadIdx.x;
  const int wave = tid >> 6, lane = tid & 63;
  const int quad = lane >> 4, l16 = lane & 15;
  const int j0 = blockIdx.x * 16;
  const int arow = 16 * wave + l16;                // batch row for A frag
  const ushort* er = inp + ((size_t)t * B_ + arow) * E_;
  const ushort* fr = feed + (size_t)arow * H_;
  const ushort* hr = h0prev + (size_t)arow * H_;
  const ushort* wih[4];
  const ushort* whh[4];
#pragma unroll
  for (int q = 0; q < 4; ++q) {
    int n = q * H_ + j0 + l16;
    wih[q] = Wih0 + (size_t)n * (E_ + H_);
    whh[q] = Whh0 + (size_t)n * H_;
  }
  const int koff = quad * 8;
  f32x4 acc[4] = {};
  for (int k0 = 0; k0 < E_ + 2 * H_; k0 += 32) {
    int kk = k0 + koff;
    short8 a;
    if (kk < E_)            a = *(const short8*)(er + kk);
    else if (kk < E_ + H_)  a = *(const short8*)(fr + (kk - E_));
    else                    a = *(const short8*)(hr + (kk - E_ - H_));
#pragma unroll
    for (int q = 0; q < 4; ++q) {
      short8 b;
      if (kk < E_ + H_) b = *(const short8*)(wih[q] + kk);
      else              b = *(const short8*)(whh[q] + (kk - E_ - H_));
      acc[q] = __builtin_amdgcn_mfma_f32_16x16x32_bf16(a, b, acc[q], 0, 0, 0);
    }
  }
  const int j = j0 + l16;
  float bsum[4];
#pragma unroll
  for (int q = 0; q < 4; ++q)
    bsum[q] = bih0[q * H_ + j] + bhh0[q * H_ + j];
#pragma unroll
  for (int reg = 0; reg < 4; ++reg) {
    int b = 16 * wave + quad * 4 + reg;
    float gi = acc[0][reg] + bsum[0];
    float gf = acc[1][reg] + bsum[1];
    float gg = acc[2][reg] + bsum[2];
    float go = acc[3][reg] + bsum[3];
    int idx = b * H_ + j;
    float cn = sigm(gf) * c0s[idx] + sigm(gi) * tanhf(gg);
    float hn = sigm(go) * tanhf(cn);
    c0s[idx] = cn;
    h0new[idx] = f2bf(hn);
    outhF[idx] = hn;
    outcF[idx] = cn;
  }
}

// ---------------------------------------------------------------------------
// Layer-1 LSTM (MFMA bf16): gates = h0n@Wih1^T + h1prev@Whh1^T + b.
__global__ __launch_bounds__(256) void k_lstm1(
    const ushort* __restrict__ h0n, const ushort* __restrict__ h1prev,
    const ushort* __restrict__ Wih1, const float* __restrict__ bih1,
    const ushort* __restrict__ Whh1, const float* __restrict__ bhh1,
    float* __restrict__ c1s, ushort* __restrict__ h1new,
    float* __restrict__ outhF, float* __restrict__ outcF) {
  const int tid = threadIdx.x;
  const int wave = tid >> 6, lane = tid & 63;
  const int quad = lane >> 4, l16 = lane & 15;
  const int j0 = blockIdx.x * 16;
  const int arow = 16 * wave + l16;
  const ushort* xr = h0n + (size_t)arow * H_;
  const ushort* hr = h1prev + (size_t)arow * H_;
  const ushort* wih[4];
  const ushort* whh[4];
#pragma unroll
  for (int q = 0; q < 4; ++q) {
    int n = q * H_ + j0 + l16;
    wih[q] = Wih1 + (size_t)n * H_;
    whh[q] = Whh1 + (size_t)n * H_;
  }
  const int koff = quad * 8;
  f32x4 acc[4] = {};
  for (int k0 = 0; k0 < 2 * H_; k0 += 32) {
    int kk = k0 + koff;
    short8 a = (kk < H_) ? *(const short8*)(xr + kk)
                         : *(const short8*)(hr + (kk - H_));
#pragma unroll
    for (int q = 0; q < 4; ++q) {
      short8 b = (kk < H_) ? *(const short8*)(wih[q] + kk)
                           : *(const short8*)(whh[q] + (kk - H_));
      acc[q] = __builtin_amdgcn_mfma_f32_16x16x32_bf16(a, b, acc[q], 0, 0, 0);
    }
  }
  const int j = j0 + l16;
  float bsum[4];
#pragma unroll
  for (int q = 0; q < 4; ++q)
    bsum[q] = bih1[q * H_ + j] + bhh1[q * H_ + j];
#pragma unroll
  for (int reg = 0; reg < 4; ++reg) {
    int b = 16 * wave + quad * 4 + reg;
    float gi = acc[0][reg] + bsum[0];
    float gf = acc[1][reg] + bsum[1];
    float gg = acc[2][reg] + bsum[2];
    float go = acc[3][reg] + bsum[3];
    int idx = b * H_ + j;
    float cn = sigm(gf) * c1s[idx] + sigm(gi) * tanhf(gg);
    float hn = sigm(go) * tanhf(cn);
    c1s[idx] = cn;
    h1new[idx] = f2bf(hn);
    outhF[idx] = hn;
    outcF[idx] = cn;
  }
}

// ---------------------------------------------------------------------------
// q = h1 @ Wa^T (MFMA).  grid = H/16 = 64 blocks.
__global__ __launch_bounds__(256) void k_q(
    const ushort* __restrict__ h1, const ushort* __restrict__ Wa,
    float* __restrict__ q) {
  const int tid = threadIdx.x;
  const int wave = tid >> 6, lane = tid & 63;
  const int quad = lane >> 4, l16 = lane & 15;
  const int j0 = blockIdx.x * 16;
  const int arow = 16 * wave + l16;
  const ushort* ar = h1 + (size_t)arow * H_;
  const ushort* wr = Wa + (size_t)(j0 + l16) * H_;
  const int koff = quad * 8;
  f32x4 acc = {};
  for (int k0 = 0; k0 < H_; k0 += 32) {
    int kk = k0 + koff;
    acc = __builtin_amdgcn_mfma_f32_16x16x32_bf16(
        *(const short8*)(ar + kk), *(const short8*)(wr + kk), acc, 0, 0, 0);
  }
  const int j = j0 + l16;
#pragma unroll
  for (int reg = 0; reg < 4; ++reg) {
    int b = 16 * wave + quad * 4 + reg;
    q[b * H_ + j] = acc[reg];
  }
}

// ---------------------------------------------------------------------------
// Attention: scores = ctx.q -> softmax -> cvec.  ctx bf16, attns f32 out.
__global__ __launch_bounds__(256) void k_attn(
    const ushort* __restrict__ ctx, const float* __restrict__ q,
    ushort* __restrict__ cvec_bf, float* __restrict__ attns, int t) {
  __shared__ float qs[H_];
  __shared__ float sc[S_];
  const int b = blockIdx.x;
  const int tid = threadIdx.x;
  const int wave = tid >> 6, lane = tid & 63;
  for (int d = tid; d < H_; d += 256) qs[d] = q[b * H_ + d];
  __syncthreads();
  for (int s = wave; s < S_; s += 4) {
    const ushort* row = ctx + ((size_t)s * B_ + b) * H_;
    float p = 0.f;
#pragma unroll
    for (int c = 0; c < H_; c += 512) {
      int d = c + lane * 8;
      short8 v = *(const short8*)(row + d);
#pragma unroll
      for (int jj = 0; jj < 8; ++jj)
        p += bf2f((ushort)v[jj]) * qs[d + jj];
    }
#pragma unroll
    for (int off = 32; off; off >>= 1) p += __shfl_down(p, off);
    if (lane == 0) sc[s] = p;
  }
  __syncthreads();
  if (wave == 0) {
    float m = fmaxf(sc[lane], sc[lane + 64]);
#pragma unroll
    for (int off = 32; off; off >>= 1) m = fmaxf(m, __shfl_down(m, off));
    m = __shfl(m, 0);
    float e0 = expf(sc[lane] - m), e1 = expf(sc[lane + 64] - m);
    float s2 = e0 + e1;
#pragma unroll
    for (int off = 32; off; off >>= 1) s2 += __shfl_down(s2, off);
    s2 = __shfl(s2, 0);
    float inv = 1.f / s2;
    sc[lane] = e0 * inv;
    sc[lane + 64] = e1 * inv;
  }
  __syncthreads();
  float* ao = attns + ((size_t)t * B_ + b) * S_;
  if (tid < S_) ao[tid] = sc[tid];
  float a0 = 0, a1 = 0, a2 = 0, a3 = 0;
  const ushort* cb = ctx + (size_t)b * H_;
  for (int s = 0; s < S_; ++s) {
    float al = sc[s];
    const ushort* r = cb + (size_t)s * B_ * H_;
    a0 += al * bf2f(r[tid]);
    a1 += al * bf2f(r[tid + 256]);
    a2 += al * bf2f(r[tid + 512]);
    a3 += al * bf2f(r[tid + 768]);
  }
  cvec_bf[b * H_ + tid] = f2bf(a0);
  cvec_bf[b * H_ + tid + 256] = f2bf(a1);
  cvec_bf[b * H_ + tid + 512] = f2bf(a2);
  cvec_bf[b * H_ + tid + 768] = f2bf(a3);
}

// ---------------------------------------------------------------------------
// attn_h = tanh([cvec|h1] @ Wout^T) (MFMA); outs f32, feed bf16.
__global__ __launch_bounds__(256) void k_outproj(
    const ushort* __restrict__ cvec, const ushort* __restrict__ h1n,
    const ushort* __restrict__ Wout, float* __restrict__ outs,
    ushort* __restrict__ feed, int t) {
  const int tid = threadIdx.x;
  const int wave = tid >> 6, lane = tid & 63;
  const int quad = lane >> 4, l16 = lane & 15;
  const int j0 = blockIdx.x * 16;
  const int arow = 16 * wave + l16;
  const ushort* cr = cvec + (size_t)arow * H_;
  const ushort* hr = h1n + (size_t)arow * H_;
  const ushort* wr = Wout + (size_t)(j0 + l16) * (2 * H_);
  const int koff = quad * 8;
  f32x4 acc = {};
  for (int k0 = 0; k0 < 2 * H_; k0 += 32) {
    int kk = k0 + koff;
    short8 a = (kk < H_) ? *(const short8*)(cr + kk)
                         : *(const short8*)(hr + (kk - H_));
    short8 b = *(const short8*)(wr + kk);
    acc = __builtin_amdgcn_mfma_f32_16x16x32_bf16(a, b, acc, 0, 0, 0);
  }
  const int j = j0 + l16;
#pragma unroll
  for (int reg = 0; reg < 4; ++reg) {
    int b = 16 * wave + quad * 4 + reg;
    float v = tanhf(acc[reg]);
    outs[(size_t)t * B_ * H_ + b * H_ + j] = v;
    feed[b * H_ + j] = f2bf(v);
  }
}

// ---------------------------------------------------------------------------
extern "C" void kernel_launch(void* const* d_in, const int* in_sizes, int n_in,
                              void* d_out, int out_size, void* d_ws, size_t ws_size,
                              hipStream_t stream) {
  const float* inpf  = (const float*)d_in[0];
  const float* ctxf  = (const float*)d_in[1];
  const float* h0in  = (const float*)d_in[2];
  const float* c0in  = (const float*)d_in[3];
  const float* Wih0f = (const float*)d_in[4];
  const float* bih0  = (const float*)d_in[5];
  const float* Whh0f = (const float*)d_in[6];
  const float* bhh0  = (const float*)d_in[7];
  const float* Wih1f = (const float*)d_in[8];
  const float* bih1  = (const float*)d_in[9];
  const float* Whh1f = (const float*)d_in[10];
  const float* bhh1  = (const float*)d_in[11];
  const float* Waf   = (const float*)d_in[12];
  const float* Woutf = (const float*)d_in[13];

  // d_out is FLOAT32, outputs concatenated in return order.
  float* out = (float*)d_out;
  float* outs  = out;                              // (T,B,H)
  float* hF    = out + (size_t)T_ * B_ * H_;       // (2,B,H)
  float* cF    = hF + 2 * B_ * H_;                 // (2,B,H)
  float* attns = cF + 2 * B_ * H_;                 // (T,B,S)

  // ws: states ~2.1 MB + bf16 tensors 65.0 MB = 67.1 MB (ws >= 67.7 MB known)
  char* p = (char*)d_ws;
  ushort* h0bf[2];
  ushort* h1bf[2];
  h0bf[0] = (ushort*)p; p += B_ * H_ * 2;
  h0bf[1] = (ushort*)p; p += B_ * H_ * 2;
  h1bf[0] = (ushort*)p; p += B_ * H_ * 2;
  h1bf[1] = (ushort*)p; p += B_ * H_ * 2;
  float* c0s  = (float*)p; p += B_ * H_ * 4;
  float* c1s  = (float*)p; p += B_ * H_ * 4;
  float* qbuf = (float*)p; p += B_ * H_ * 4;
  ushort* feed = (ushort*)p; p += B_ * H_ * 2;
  ushort* cvec = (ushort*)p; p += B_ * H_ * 2;

  // bf16 conversions: weights + inp + ctx (biases stay f32)
  struct { const float* src; int n; } cv[8] = {
    {Wih0f, 4 * H_ * (E_ + H_)}, {Whh0f, 4 * H_ * H_},
    {Wih1f, 4 * H_ * H_},        {Whh1f, 4 * H_ * H_},
    {Waf,   H_ * H_},            {Woutf, 2 * H_ * H_},
    {inpf,  T_ * B_ * E_},       {ctxf,  S_ * B_ * H_},
  };
  ushort* cb[8];
  for (int i = 0; i < 8; ++i) {
    cb[i] = (ushort*)p; p += (size_t)cv[i].n * 2;
    int n4 = cv[i].n / 4;
    k_cvt<<<(n4 + 255) / 256, 256, 0, stream>>>(cv[i].src, cb[i], n4);
  }
  const ushort *Wih0 = cb[0], *Whh0 = cb[1], *Wih1 = cb[2], *Whh1 = cb[3],
               *Wa = cb[4], *Wout = cb[5], *inp = cb[6], *ctx = cb[7];

  k_init<<<(B_ * H_) / 256, 256, 0, stream>>>(h0in, c0in, h0bf[0], h1bf[0],
                                              c0s, c1s, feed);

  for (int t = 0; t < T_; ++t) {
    int cur = t & 1;
    k_lstm0<<<H_ / 16, 256, 0, stream>>>(inp, Wih0, bih0, Whh0, bhh0, feed,
                                         h0bf[cur], c0s, h0bf[cur ^ 1],
                                         hF, cF, t);
    k_lstm1<<<H_ / 16, 256, 0, stream>>>(h0bf[cur ^ 1], h1bf[cur], Wih1, bih1,
                                         Whh1, bhh1, c1s, h1bf[cur ^ 1],
                                         hF + B_ * H_, cF + B_ * H_);
    k_q<<<H_ / 16, 256, 0, stream>>>(h1bf[cur ^ 1], Wa, qbuf);
    k_attn<<<B_, 256, 0, stream>>>(ctx, qbuf, cvec, attns, t);
    k_outproj<<<H_ / 16, 256, 0, stream>>>(cvec, h1bf[cur ^ 1], Wout, outs,
                                           feed, t);
  }
}

// Round 9
// 5787.841 us; speedup vs baseline: 13.2339x; 1.6613x over previous
//
#include <hip/hip_runtime.h>

#define T_ 64
#define B_ 64
#define S_ 128
#define E_ 512
#define H_ 1024

typedef __attribute__((ext_vector_type(8))) short short8;
typedef __attribute__((ext_vector_type(4))) short short4v;
typedef __attribute__((ext_vector_type(4))) float f32x4;

static __device__ __forceinline__ float bf2f(ushort u) {
  union { float f; unsigned u; } x; x.u = ((unsigned)u) << 16; return x.f;
}
static __device__ __forceinline__ ushort f2bf(float f) {
  union { float f; unsigned u; } x; x.f = f;
  unsigned r = 0x7FFFu + ((x.u >> 16) & 1u);
  return (ushort)((x.u + r) >> 16);
}
static __device__ __forceinline__ float sigm(float x) {
  return 1.f / (1.f + expf(-x));
}

// ---------------------------------------------------------------------------
__global__ __launch_bounds__(256) void k_cvt(const float* __restrict__ src,
                                             ushort* __restrict__ dst, int n4) {
  int i = blockIdx.x * 256 + threadIdx.x;
  if (i >= n4) return;
  f32x4 v = ((const f32x4*)src)[i];
  short4v o;
  o[0] = (short)f2bf(v[0]); o[1] = (short)f2bf(v[1]);
  o[2] = (short)f2bf(v[2]); o[3] = (short)f2bf(v[3]);
  ((short4v*)dst)[i] = o;
}

// ---------------------------------------------------------------------------
__global__ __launch_bounds__(256) void k_init(const float* __restrict__ h0in,
                                              const float* __restrict__ c0in,
                                              ushort* __restrict__ h0bf,
                                              ushort* __restrict__ h1bf,
                                              float* __restrict__ c0s,
                                              float* __restrict__ c1s,
                                              ushort* __restrict__ feed) {
  int i = blockIdx.x * 256 + threadIdx.x;
  h0bf[i] = f2bf(h0in[i]);
  h1bf[i] = f2bf(h0in[B_ * H_ + i]);
  c0s[i] = c0in[i];
  c1s[i] = c0in[B_ * H_ + i];
  feed[i] = 0;
}

// ---------------------------------------------------------------------------
// Layer-0 LSTM, gate-packed MFMA: grid = H/4 = 256 blocks. Block owns j-cols
// [j0,j0+4) x all 4 gates packed into one 16-wide MFMA N-tile
// (lane l16 -> gate l16>>2, col j0+(l16&3)). 4 waves = 4 batch strips of 16.
__global__ __launch_bounds__(256) void k_lstm0(
    const ushort* __restrict__ inp, const ushort* __restrict__ Wih0,
    const float* __restrict__ bih0, const ushort* __restrict__ Whh0,
    const float* __restrict__ bhh0, const ushort* __restrict__ feed,
    const ushort* __restrict__ h0prev, float* __restrict__ c0s,
    ushort* __restrict__ h0new, float* __restrict__ outhF,
    float* __restrict__ outcF, int t, int last) {
  __shared__ float st[4][16][17];
  const int tid = threadIdx.x;
  const int wave = tid >> 6, lane = tid & 63;
  const int quad = lane >> 4, l16 = lane & 15;
  const int j0 = blockIdx.x * 4;
  const int arow = 16 * wave + l16;                     // batch row (A frag)
  const ushort* er = inp + ((size_t)t * B_ + arow) * E_;
  const ushort* fr = feed + (size_t)arow * H_;
  const ushort* hr = h0prev + (size_t)arow * H_;
  const int n = (l16 >> 2) * H_ + j0 + (l16 & 3);       // packed gate row
  const ushort* wihB = Wih0 + (size_t)n * (E_ + H_);
  const ushort* whhB = Whh0 + (size_t)n * H_;
  const int koff = quad * 8;
  f32x4 acc = {};
  for (int k0 = 0; k0 < E_ + 2 * H_; k0 += 32) {
    int kk = k0 + koff;
    short8 a;
    if (kk < E_)            a = *(const short8*)(er + kk);
    else if (kk < E_ + H_)  a = *(const short8*)(fr + (kk - E_));
    else                    a = *(const short8*)(hr + (kk - E_ - H_));
    short8 b = (kk < E_ + H_) ? *(const short8*)(wihB + kk)
                              : *(const short8*)(whhB + (kk - E_ - H_));
    acc = __builtin_amdgcn_mfma_f32_16x16x32_bf16(a, b, acc, 0, 0, 0);
  }
  // stage wave-local 16x16 C-tile (rows=batches, cols=packed gate/j)
#pragma unroll
  for (int reg = 0; reg < 4; ++reg)
    st[wave][quad * 4 + reg][l16] = acc[reg];
  // wave-local consumption: no __syncthreads needed
  const int bl = lane & 15;          // local batch row
  const int jj = lane >> 4;          // local j (0..3)
  const int b = 16 * wave + bl;
  const int j = j0 + jj;
  float gi = st[wave][bl][0 + jj]  + bih0[0 * H_ + j] + bhh0[0 * H_ + j];
  float gf = st[wave][bl][4 + jj]  + bih0[1 * H_ + j] + bhh0[1 * H_ + j];
  float gg = st[wave][bl][8 + jj]  + bih0[2 * H_ + j] + bhh0[2 * H_ + j];
  float go = st[wave][bl][12 + jj] + bih0[3 * H_ + j] + bhh0[3 * H_ + j];
  const int idx = b * H_ + j;
  float cn = sigm(gf) * c0s[idx] + sigm(gi) * tanhf(gg);
  float hn = sigm(go) * tanhf(cn);
  c0s[idx] = cn;
  h0new[idx] = f2bf(hn);
  if (last) { outhF[idx] = hn; outcF[idx] = cn; }
}

// ---------------------------------------------------------------------------
// Layer-1 LSTM, gate-packed MFMA: grid = H/4 = 256 blocks.
__global__ __launch_bounds__(256) void k_lstm1(
    const ushort* __restrict__ h0n, const ushort* __restrict__ h1prev,
    const ushort* __restrict__ Wih1, const float* __restrict__ bih1,
    const ushort* __restrict__ Whh1, const float* __restrict__ bhh1,
    float* __restrict__ c1s, ushort* __restrict__ h1new,
    float* __restrict__ outhF, float* __restrict__ outcF, int last) {
  __shared__ float st[4][16][17];
  const int tid = threadIdx.x;
  const int wave = tid >> 6, lane = tid & 63;
  const int quad = lane >> 4, l16 = lane & 15;
  const int j0 = blockIdx.x * 4;
  const int arow = 16 * wave + l16;
  const ushort* xr = h0n + (size_t)arow * H_;
  const ushort* hr = h1prev + (size_t)arow * H_;
  const int n = (l16 >> 2) * H_ + j0 + (l16 & 3);
  const ushort* wihB = Wih1 + (size_t)n * H_;
  const ushort* whhB = Whh1 + (size_t)n * H_;
  const int koff = quad * 8;
  f32x4 acc = {};
  for (int k0 = 0; k0 < 2 * H_; k0 += 32) {
    int kk = k0 + koff;
    short8 a = (kk < H_) ? *(const short8*)(xr + kk)
                         : *(const short8*)(hr + (kk - H_));
    short8 b = (kk < H_) ? *(const short8*)(wihB + kk)
                         : *(const short8*)(whhB + (kk - H_));
    acc = __builtin_amdgcn_mfma_f32_16x16x32_bf16(a, b, acc, 0, 0, 0);
  }
#pragma unroll
  for (int reg = 0; reg < 4; ++reg)
    st[wave][quad * 4 + reg][l16] = acc[reg];
  const int bl = lane & 15;
  const int jj = lane >> 4;
  const int b = 16 * wave + bl;
  const int j = j0 + jj;
  float gi = st[wave][bl][0 + jj]  + bih1[0 * H_ + j] + bhh1[0 * H_ + j];
  float gf = st[wave][bl][4 + jj]  + bih1[1 * H_ + j] + bhh1[1 * H_ + j];
  float gg = st[wave][bl][8 + jj]  + bih1[2 * H_ + j] + bhh1[2 * H_ + j];
  float go = st[wave][bl][12 + jj] + bih1[3 * H_ + j] + bhh1[3 * H_ + j];
  const int idx = b * H_ + j;
  float cn = sigm(gf) * c1s[idx] + sigm(gi) * tanhf(gg);
  float hn = sigm(go) * tanhf(cn);
  c1s[idx] = cn;
  h1new[idx] = f2bf(hn);
  if (last) { outhF[idx] = hn; outcF[idx] = cn; }
}

// ---------------------------------------------------------------------------
// q = h1 @ Wa^T (MFMA).  grid = H/16 = 64 blocks (only 2 MB streamed).
__global__ __launch_bounds__(256) void k_q(
    const ushort* __restrict__ h1, const ushort* __restrict__ Wa,
    float* __restrict__ q) {
  const int tid = threadIdx.x;
  const int wave = tid >> 6, lane = tid & 63;
  const int quad = lane >> 4, l16 = lane & 15;
  const int j0 = blockIdx.x * 16;
  const int arow = 16 * wave + l16;
  const ushort* ar = h1 + (size_t)arow * H_;
  const ushort* wr = Wa + (size_t)(j0 + l16) * H_;
  const int koff = quad * 8;
  f32x4 acc = {};
  for (int k0 = 0; k0 < H_; k0 += 32) {
    int kk = k0 + koff;
    acc = __builtin_amdgcn_mfma_f32_16x16x32_bf16(
        *(const short8*)(ar + kk), *(const short8*)(wr + kk), acc, 0, 0, 0);
  }
  const int j = j0 + l16;
#pragma unroll
  for (int reg = 0; reg < 4; ++reg) {
    int b = 16 * wave + quad * 4 + reg;
    q[b * H_ + j] = acc[reg];
  }
}

// ---------------------------------------------------------------------------
// scores[b,s] = ctx[s,b,:] . q[b,:]   grid = (B, 4), block = 32 s-values.
__global__ __launch_bounds__(256) void k_score(
    const ushort* __restrict__ ctx, const float* __restrict__ q,
    float* __restrict__ scores) {
  __shared__ float qs[H_];
  const int b = blockIdx.x;
  const int tid = threadIdx.x;
  const int wave = tid >> 6, lane = tid & 63;
  for (int d = tid; d < H_; d += 256) qs[d] = q[b * H_ + d];
  __syncthreads();
  const int s0 = blockIdx.y * 32 + wave * 8;
#pragma unroll
  for (int i = 0; i < 8; ++i) {
    int s = s0 + i;
    const ushort* row = ctx + ((size_t)s * B_ + b) * H_;
    float p = 0.f;
#pragma unroll
    for (int c = 0; c < H_; c += 512) {
      int d = c + lane * 8;
      short8 v = *(const short8*)(row + d);
#pragma unroll
      for (int jj = 0; jj < 8; ++jj)
        p += bf2f((ushort)v[jj]) * qs[d + jj];
    }
#pragma unroll
    for (int off = 32; off; off >>= 1) p += __shfl_down(p, off);
    if (lane == 0) scores[b * S_ + s] = p;
  }
}

// ---------------------------------------------------------------------------
// softmax (redundant per block, cheap) + cvec d-chunk.  grid = (B, 4).
__global__ __launch_bounds__(256) void k_attnsm(
    const ushort* __restrict__ ctx, const float* __restrict__ scores,
    ushort* __restrict__ cvec_bf, float* __restrict__ attns, int t) {
  __shared__ float al[S_];
  const int b = blockIdx.x;
  const int tid = threadIdx.x;
  const int wave = tid >> 6, lane = tid & 63;
  if (tid < S_) al[tid] = scores[b * S_ + tid];
  __syncthreads();
  if (wave == 0) {
    float m = fmaxf(al[lane], al[lane + 64]);
#pragma unroll
    for (int off = 32; off; off >>= 1) m = fmaxf(m, __shfl_down(m, off));
    m = __shfl(m, 0);
    float e0 = expf(al[lane] - m), e1 = expf(al[lane + 64] - m);
    float s2 = e0 + e1;
#pragma unroll
    for (int off = 32; off; off >>= 1) s2 += __shfl_down(s2, off);
    s2 = __shfl(s2, 0);
    float inv = 1.f / s2;
    al[lane] = e0 * inv;
    al[lane + 64] = e1 * inv;
  }
  __syncthreads();
  if (blockIdx.y == 0 && tid < S_)
    attns[((size_t)t * B_ + b) * S_ + tid] = al[tid];
  const int d = blockIdx.y * 256 + tid;
  const ushort* cb = ctx + (size_t)b * H_ + d;
  float a = 0.f;
#pragma unroll 4
  for (int s = 0; s < S_; ++s)
    a += al[s] * bf2f(cb[(size_t)s * B_ * H_]);
  cvec_bf[b * H_ + d] = f2bf(a);
}

// ---------------------------------------------------------------------------
// attn_h = tanh([cvec|h1] @ Wout^T) (MFMA); outs f32, feed bf16. grid=64.
__global__ __launch_bounds__(256) void k_outproj(
    const ushort* __restrict__ cvec, const ushort* __restrict__ h1n,
    const ushort* __restrict__ Wout, float* __restrict__ outs,
    ushort* __restrict__ feed, int t) {
  const int tid = threadIdx.x;
  const int wave = tid >> 6, lane = tid & 63;
  const int quad = lane >> 4, l16 = lane & 15;
  const int j0 = blockIdx.x * 16;
  const int arow = 16 * wave + l16;
  const ushort* cr = cvec + (size_t)arow * H_;
  const ushort* hr = h1n + (size_t)arow * H_;
  const ushort* wr = Wout + (size_t)(j0 + l16) * (2 * H_);
  const int koff = quad * 8;
  f32x4 acc = {};
  for (int k0 = 0; k0 < 2 * H_; k0 += 32) {
    int kk = k0 + koff;
    short8 a = (kk < H_) ? *(const short8*)(cr + kk)
                         : *(const short8*)(hr + (kk - H_));
    short8 b = *(const short8*)(wr + kk);
    acc = __builtin_amdgcn_mfma_f32_16x16x32_bf16(a, b, acc, 0, 0, 0);
  }
  const int j = j0 + l16;
#pragma unroll
  for (int reg = 0; reg < 4; ++reg) {
    int b = 16 * wave + quad * 4 + reg;
    float v = tanhf(acc[reg]);
    outs[(size_t)t * B_ * H_ + b * H_ + j] = v;
    feed[b * H_ + j] = f2bf(v);
  }
}

// ---------------------------------------------------------------------------
extern "C" void kernel_launch(void* const* d_in, const int* in_sizes, int n_in,
                              void* d_out, int out_size, void* d_ws, size_t ws_size,
                              hipStream_t stream) {
  const float* inpf  = (const float*)d_in[0];
  const float* ctxf  = (const float*)d_in[1];
  const float* h0in  = (const float*)d_in[2];
  const float* c0in  = (const float*)d_in[3];
  const float* Wih0f = (const float*)d_in[4];
  const float* bih0  = (const float*)d_in[5];
  const float* Whh0f = (const float*)d_in[6];
  const float* bhh0  = (const float*)d_in[7];
  const float* Wih1f = (const float*)d_in[8];
  const float* bih1  = (const float*)d_in[9];
  const float* Whh1f = (const float*)d_in[10];
  const float* bhh1  = (const float*)d_in[11];
  const float* Waf   = (const float*)d_in[12];
  const float* Woutf = (const float*)d_in[13];

  float* out = (float*)d_out;
  float* outs  = out;                              // (T,B,H)
  float* hF    = out + (size_t)T_ * B_ * H_;       // (2,B,H)
  float* cF    = hF + 2 * B_ * H_;                 // (2,B,H)
  float* attns = cF + 2 * B_ * H_;                 // (T,B,S)

  char* p = (char*)d_ws;
  ushort* h0bf[2];
  ushort* h1bf[2];
  h0bf[0] = (ushort*)p; p += B_ * H_ * 2;
  h0bf[1] = (ushort*)p; p += B_ * H_ * 2;
  h1bf[0] = (ushort*)p; p += B_ * H_ * 2;
  h1bf[1] = (ushort*)p; p += B_ * H_ * 2;
  float* c0s  = (float*)p; p += B_ * H_ * 4;
  float* c1s  = (float*)p; p += B_ * H_ * 4;
  float* qbuf = (float*)p; p += B_ * H_ * 4;
  float* sbuf = (float*)p; p += B_ * S_ * 4;
  ushort* feed = (ushort*)p; p += B_ * H_ * 2;
  ushort* cvec = (ushort*)p; p += B_ * H_ * 2;

  struct { const float* src; int n; } cv[8] = {
    {Wih0f, 4 * H_ * (E_ + H_)}, {Whh0f, 4 * H_ * H_},
    {Wih1f, 4 * H_ * H_},        {Whh1f, 4 * H_ * H_},
    {Waf,   H_ * H_},            {Woutf, 2 * H_ * H_},
    {inpf,  T_ * B_ * E_},       {ctxf,  S_ * B_ * H_},
  };
  ushort* cb[8];
  for (int i = 0; i < 8; ++i) {
    cb[i] = (ushort*)p; p += (size_t)cv[i].n * 2;
    int n4 = cv[i].n / 4;
    k_cvt<<<(n4 + 255) / 256, 256, 0, stream>>>(cv[i].src, cb[i], n4);
  }
  const ushort *Wih0 = cb[0], *Whh0 = cb[1], *Wih1 = cb[2], *Whh1 = cb[3],
               *Wa = cb[4], *Wout = cb[5], *inp = cb[6], *ctx = cb[7];

  k_init<<<(B_ * H_) / 256, 256, 0, stream>>>(h0in, c0in, h0bf[0], h1bf[0],
                                              c0s, c1s, feed);

  for (int t = 0; t < T_; ++t) {
    int cur = t & 1;
    int last = (t == T_ - 1) ? 1 : 0;
    k_lstm0<<<H_ / 4, 256, 0, stream>>>(inp, Wih0, bih0, Whh0, bhh0, feed,
                                        h0bf[cur], c0s, h0bf[cur ^ 1],
                                        hF, cF, t, last);
    k_lstm1<<<H_ / 4, 256, 0, stream>>>(h0bf[cur ^ 1], h1bf[cur], Wih1, bih1,
                                        Whh1, bhh1, c1s, h1bf[cur ^ 1],
                                        hF + B_ * H_, cF + B_ * H_, last);
    k_q<<<H_ / 16, 256, 0, stream>>>(h1bf[cur ^ 1], Wa, qbuf);
    k_score<<<dim3(B_, 4), 256, 0, stream>>>(ctx, qbuf, sbuf);
    k_attnsm<<<dim3(B_, 4), 256, 0, stream>>>(ctx, sbuf, cvec, attns, t);
    k_outproj<<<H_ / 16, 256, 0, stream>>>(cvec, h1bf[cur ^ 1], Wout, outs,
                                           feed, t);
  }
}